// Round 1
// baseline (227.083 us; speedup 1.0000x reference)
//
#include <hip/hip_runtime.h>
#include <hip/hip_bf16.h>

typedef __attribute__((ext_vector_type(8))) short short8;
typedef __attribute__((ext_vector_type(4))) float floatx4;
typedef __attribute__((ext_vector_type(8))) unsigned short ushortx8;
typedef __attribute__((ext_vector_type(4))) unsigned short ushortx4;
typedef unsigned short u16;

#define HIDDEN 1024
#define NH 16
#define HD 64
#define SEQ 2048
#define CHUNK 128
#define NCHUNK (SEQ / CHUNK)  // 16

__device__ __forceinline__ u16 f2bf(float f) {
    union { float f; unsigned u; } v; v.f = f;
    unsigned r = v.u + 0x7fffu + ((v.u >> 16) & 1u);
    return (u16)(r >> 16);
}
__device__ __forceinline__ float bf2f(u16 u) {
    union { unsigned u; float f; } v; v.u = ((unsigned)u) << 16;
    return v.f;
}

// ---------------------------------------------------------------------------
// Kernel 1: fused QKV GEMM. q/k/v[l][n] = sum_k x[l][k]*W[n][k], elu+1 on q,k.
// A = x (fp32, row-major, K-contig), B = W (fp32, row-major = B^T layout).
// 128x128 tile, 4 waves, each wave 64x64 (4x4 MFMA tiles), BK=64.
// grid (24, 16): bn>>3 selects Wq/Wk/Wv.
// ---------------------------------------------------------------------------
__global__ __launch_bounds__(256, 2)
void qkv_gemm(const float* __restrict__ x, const float* __restrict__ Wq,
              const float* __restrict__ Wk, const float* __restrict__ Wv,
              u16* __restrict__ qb, u16* __restrict__ kb, u16* __restrict__ vb)
{
    __shared__ u16 As[128 * 72];  // +8 pad: 2-way LDS bank aliasing (free)
    __shared__ u16 Bs[128 * 72];
    const int bn = blockIdx.x, bm = blockIdx.y;
    const int grp = bn >> 3;
    const float* __restrict__ W = (grp == 0) ? Wq : (grp == 1) ? Wk : Wv;
    const int n0 = (bn & 7) * 128;
    const int m0 = bm * 128;
    const int t = threadIdx.x;
    const int lane = t & 63, wave = t >> 6;
    const int ln = lane & 15, q4 = lane >> 4;
    const int wm = (wave >> 1) * 64, wn = (wave & 1) * 64;
    const int srow = t >> 1, sc = (t & 1) * 32;

    floatx4 acc[4][4];
#pragma unroll
    for (int i = 0; i < 4; i++)
#pragma unroll
        for (int j = 0; j < 4; j++) acc[i][j] = (floatx4)0.0f;

    for (int k0 = 0; k0 < HIDDEN; k0 += 64) {
        const float4* ga = (const float4*)(x + (size_t)(m0 + srow) * HIDDEN + k0 + sc);
        const float4* gb = (const float4*)(W + (size_t)(n0 + srow) * HIDDEN + k0 + sc);
        float4 av[8], bv[8];
#pragma unroll
        for (int i = 0; i < 8; i++) av[i] = ga[i];
#pragma unroll
        for (int i = 0; i < 8; i++) bv[i] = gb[i];
        __syncthreads();
        u16* pa = &As[srow * 72 + sc];
        u16* pb = &Bs[srow * 72 + sc];
#pragma unroll
        for (int i = 0; i < 8; i++) {
            ushortx4 ua = { f2bf(av[i].x), f2bf(av[i].y), f2bf(av[i].z), f2bf(av[i].w) };
            *(ushortx4*)(pa + i * 4) = ua;
            ushortx4 ub = { f2bf(bv[i].x), f2bf(bv[i].y), f2bf(bv[i].z), f2bf(bv[i].w) };
            *(ushortx4*)(pb + i * 4) = ub;
        }
        __syncthreads();
#pragma unroll
        for (int s = 0; s < 2; s++) {
            short8 af[4], bfr[4];
#pragma unroll
            for (int i = 0; i < 4; i++)
                af[i] = *(const short8*)&As[(wm + i * 16 + ln) * 72 + s * 32 + q4 * 8];
#pragma unroll
            for (int j = 0; j < 4; j++)
                bfr[j] = *(const short8*)&Bs[(wn + j * 16 + ln) * 72 + s * 32 + q4 * 8];
#pragma unroll
            for (int i = 0; i < 4; i++)
#pragma unroll
                for (int j = 0; j < 4; j++)
                    acc[i][j] = __builtin_amdgcn_mfma_f32_16x16x32_bf16(af[i], bfr[j], acc[i][j], 0, 0, 0);
        }
    }
    u16* __restrict__ outp = (grp == 0) ? qb : (grp == 1) ? kb : vb;
    const bool elu = (grp < 2);
    // C/D layout: row = q4*4 + r, col = ln
#pragma unroll
    for (int i = 0; i < 4; i++)
#pragma unroll
        for (int j = 0; j < 4; j++)
#pragma unroll
            for (int r = 0; r < 4; r++) {
                int m = m0 + wm + i * 16 + q4 * 4 + r;
                int n = n0 + wn + j * 16 + ln;
                float v = acc[i][j][r];
                if (elu) v = (v > 0.f) ? (v + 1.f) : __expf(v);
                outp[(size_t)m * HIDDEN + n] = f2bf(v);
            }
}

// ---------------------------------------------------------------------------
// Kernel 2: per-(chunk,head) state S_c[d][e] = sum_j K[j][d]*V[j][e] via MFMA
// (A = K^T staged transposed, B wants [e][j] = V^T staged transposed).
// Stores S^T (e-major) so kernel 3 reads contiguous. Also ksum[d].
// grid (16, 16).
// ---------------------------------------------------------------------------
__global__ __launch_bounds__(256, 2)
void chunk_stats(const u16* __restrict__ kb, const u16* __restrict__ vb,
                 float* __restrict__ S_ws, float* __restrict__ ksum_ws)
{
    __shared__ u16 kT[64 * 136];
    __shared__ u16 vT[64 * 136];
    const int c = blockIdx.x, h = blockIdx.y;
    const int t = threadIdx.x;
    const int lane = t & 63, wave = t >> 6;
    const int ln = lane & 15, q4 = lane >> 4;
    {
        const int row = t >> 1, sc = (t & 1) * 32;
        const size_t gbase = (size_t)(c * CHUNK + row) * HIDDEN + h * HD + sc;
        u16 kr[32], vr[32];
#pragma unroll
        for (int i = 0; i < 4; i++) {
            *(ushortx8*)&kr[i * 8] = *(const ushortx8*)(kb + gbase + i * 8);
            *(ushortx8*)&vr[i * 8] = *(const ushortx8*)(vb + gbase + i * 8);
        }
#pragma unroll
        for (int j = 0; j < 32; j++) {
            kT[(sc + j) * 136 + row] = kr[j];
            vT[(sc + j) * 136 + row] = vr[j];
        }
    }
    __syncthreads();
    floatx4 sacc[4];
#pragma unroll
    for (int j = 0; j < 4; j++) sacc[j] = (floatx4)0.0f;
#pragma unroll
    for (int ks = 0; ks < 4; ks++) {
        short8 af = *(const short8*)&kT[(wave * 16 + ln) * 136 + ks * 32 + q4 * 8];
#pragma unroll
        for (int j = 0; j < 4; j++) {
            short8 bfr = *(const short8*)&vT[(j * 16 + ln) * 136 + ks * 32 + q4 * 8];
            sacc[j] = __builtin_amdgcn_mfma_f32_16x16x32_bf16(af, bfr, sacc[j], 0, 0, 0);
        }
    }
    float* Sp = S_ws + ((size_t)(h * NCHUNK + c) << 12);
#pragma unroll
    for (int j = 0; j < 4; j++)
#pragma unroll
        for (int r = 0; r < 4; r++) {
            int d = wave * 16 + q4 * 4 + r;
            int e = j * 16 + ln;
            Sp[e * 64 + d] = sacc[j][r];  // S^T layout [e][d]
        }
    if (t < 64) {
        float s = 0.f;
#pragma unroll
        for (int j = 0; j < 128; j++) s += bf2f(kT[t * 136 + j]);
        ksum_ws[(h * NCHUNK + c) * 64 + t] = s;
    }
}

// ---------------------------------------------------------------------------
// Kernel 3: attention output per (chunk, head).
//   KV_prefix = sum_{c'<c} S_c'  (on-the-fly from S_ws, L2-resident)
//   P = QK^T (causal-masked), denom = rowsum(P) + q.kpref
//   O = P V + Q KV_prefix; attn = O / denom
// LDS budget 64768 B: P_l (bf16 A-layout round trip) aliases dead q_l/k_l.
// grid (16, 16).
// ---------------------------------------------------------------------------
__global__ __launch_bounds__(256, 1)
void attn_out(const u16* __restrict__ qb, const u16* __restrict__ kb,
              const u16* __restrict__ vb, const float* __restrict__ S_ws,
              const float* __restrict__ ksum_ws, u16* __restrict__ attnb)
{
    __shared__ __align__(16) u16 smem[32384];  // 64768 B
    u16* q_l   = smem;          // [128][72]
    u16* k_l   = smem + 9216;   // [128][72]
    u16* P_l   = smem;          // [128][136] — aliases q_l+k_l after both dead
    u16* vT_l  = smem + 18432;  // [64][136]  V^T
    u16* kvT_l = smem + 27136;  // [64][72]   KV_prefix^T (bf16)
    float* kpref  = (float*)(smem + 31744);  // [64]
    float* denom2 = kpref + 64;              // [2][128]

    const int c = blockIdx.x, h = blockIdx.y;
    const int t = threadIdx.x;
    const int lane = t & 63, wave = t >> 6;
    const int ln = lane & 15, q4 = lane >> 4;

    // --- stage q,k row-major; v transposed ---
    {
        const int row = t >> 1, sc = (t & 1) * 32;
        const size_t gbase = (size_t)(c * CHUNK + row) * HIDDEN + h * HD + sc;
#pragma unroll
        for (int i = 0; i < 4; i++) {
            *(ushortx8*)&q_l[row * 72 + sc + i * 8] = *(const ushortx8*)(qb + gbase + i * 8);
            *(ushortx8*)&k_l[row * 72 + sc + i * 8] = *(const ushortx8*)(kb + gbase + i * 8);
        }
        u16 vr[32];
#pragma unroll
        for (int i = 0; i < 4; i++) *(ushortx8*)&vr[i * 8] = *(const ushortx8*)(vb + gbase + i * 8);
#pragma unroll
        for (int j = 0; j < 32; j++) vT_l[(sc + j) * 136 + row] = vr[j];
    }
    // --- KV prefix accumulation (thread owns e = t>>2, 16 d's) ---
    {
        const int e = t >> 2, db = (t & 3) * 16;
        float kv[16];
#pragma unroll
        for (int i = 0; i < 16; i++) kv[i] = 0.f;
        for (int cp = 0; cp < c; cp++) {
            const float* Sp = S_ws + ((size_t)(h * NCHUNK + cp) << 12) + e * 64 + db;
#pragma unroll
            for (int g = 0; g < 4; g++) {
                float4 s4 = *(const float4*)(Sp + g * 4);
                kv[g * 4 + 0] += s4.x; kv[g * 4 + 1] += s4.y;
                kv[g * 4 + 2] += s4.z; kv[g * 4 + 3] += s4.w;
            }
        }
#pragma unroll
        for (int g = 0; g < 4; g++) {
            ushortx4 u = { f2bf(kv[g * 4 + 0]), f2bf(kv[g * 4 + 1]),
                           f2bf(kv[g * 4 + 2]), f2bf(kv[g * 4 + 3]) };
            *(ushortx4*)&kvT_l[e * 72 + db + g * 4] = u;
        }
        if (t < 64) {
            float s = 0.f;
            for (int cp = 0; cp < c; cp++) s += ksum_ws[(h * NCHUNK + cp) * 64 + t];
            kpref[t] = s;
        }
    }
    __syncthreads();

    // --- P = QK^T : wave quadrant (pm, pn), 64x64, K=64 ---
    const int pm = (wave >> 1) * 64, pn = (wave & 1) * 64;
    floatx4 pacc[4][4];
#pragma unroll
    for (int i = 0; i < 4; i++)
#pragma unroll
        for (int j = 0; j < 4; j++) pacc[i][j] = (floatx4)0.0f;
#pragma unroll
    for (int s = 0; s < 2; s++) {
        short8 af[4], bfr[4];
#pragma unroll
        for (int i = 0; i < 4; i++)
            af[i] = *(const short8*)&q_l[(pm + i * 16 + ln) * 72 + s * 32 + q4 * 8];
#pragma unroll
        for (int j = 0; j < 4; j++)
            bfr[j] = *(const short8*)&k_l[(pn + j * 16 + ln) * 72 + s * 32 + q4 * 8];
#pragma unroll
        for (int i = 0; i < 4; i++)
#pragma unroll
            for (int j = 0; j < 4; j++)
                pacc[i][j] = __builtin_amdgcn_mfma_f32_16x16x32_bf16(af[i], bfr[j], pacc[i][j], 0, 0, 0);
    }
    // --- causal mask + rowsum (denominator part) ---
#pragma unroll
    for (int i = 0; i < 4; i++)
#pragma unroll
        for (int r = 0; r < 4; r++) {
            int rowi = pm + i * 16 + q4 * 4 + r;
            float rs = 0.f;
#pragma unroll
            for (int j = 0; j < 4; j++) {
                int col = pn + j * 16 + ln;
                float p = pacc[i][j][r];
                if (col > rowi) p = 0.f;
                pacc[i][j][r] = p;
                rs += p;
            }
#pragma unroll
            for (int off = 1; off < 16; off <<= 1) rs += __shfl_xor(rs, off, 64);
            if (ln == 0) denom2[(wave & 1) * 128 + rowi] = rs;
        }
    // --- O_inter = Q @ KV_prefix : wave rows ob..ob+31, cols 0..63 ---
    const int ob = wave * 32;
    floatx4 oacc[2][4];
#pragma unroll
    for (int i = 0; i < 2; i++)
#pragma unroll
        for (int j = 0; j < 4; j++) oacc[i][j] = (floatx4)0.0f;
#pragma unroll
    for (int s = 0; s < 2; s++) {
        short8 af[2], bfr[4];
#pragma unroll
        for (int i2 = 0; i2 < 2; i2++)
            af[i2] = *(const short8*)&q_l[(ob + i2 * 16 + ln) * 72 + s * 32 + q4 * 8];
#pragma unroll
        for (int j = 0; j < 4; j++)
            bfr[j] = *(const short8*)&kvT_l[(j * 16 + ln) * 72 + s * 32 + q4 * 8];
#pragma unroll
        for (int i2 = 0; i2 < 2; i2++)
#pragma unroll
            for (int j = 0; j < 4; j++)
                oacc[i2][j] = __builtin_amdgcn_mfma_f32_16x16x32_bf16(af[i2], bfr[j], oacc[i2][j], 0, 0, 0);
    }
    __syncthreads();  // denom2 rowsums visible; all q_l/k_l reads done
    // --- denominator inter part: q_i . kpref ---
    if (t < 128) {
        float s = 0.f;
#pragma unroll
        for (int d = 0; d < 64; d++) s += bf2f(q_l[t * 72 + d]) * kpref[d];
        denom2[t] += s;  // slot [0][t]
    }
    __syncthreads();  // q_l reads done; safe to overwrite with P
    // --- write masked P (bf16) into aliased LDS ---
#pragma unroll
    for (int i = 0; i < 4; i++)
#pragma unroll
        for (int j = 0; j < 4; j++)
#pragma unroll
            for (int r = 0; r < 4; r++) {
                int rowi = pm + i * 16 + q4 * 4 + r;
                int col = pn + j * 16 + ln;
                P_l[rowi * 136 + col] = f2bf(pacc[i][j][r]);
            }
    __syncthreads();
    // --- O_intra = P @ V : K=128, causal skip (ks <= wave) ---
    for (int ks = 0; ks <= wave; ks++) {
        short8 af[2], bfr[4];
#pragma unroll
        for (int i2 = 0; i2 < 2; i2++)
            af[i2] = *(const short8*)&P_l[(ob + i2 * 16 + ln) * 136 + ks * 32 + q4 * 8];
#pragma unroll
        for (int j = 0; j < 4; j++)
            bfr[j] = *(const short8*)&vT_l[(j * 16 + ln) * 136 + ks * 32 + q4 * 8];
#pragma unroll
        for (int i2 = 0; i2 < 2; i2++)
#pragma unroll
            for (int j = 0; j < 4; j++)
                oacc[i2][j] = __builtin_amdgcn_mfma_f32_16x16x32_bf16(af[i2], bfr[j], oacc[i2][j], 0, 0, 0);
    }
    // --- normalize + store ---
#pragma unroll
    for (int i2 = 0; i2 < 2; i2++)
#pragma unroll
        for (int j = 0; j < 4; j++)
#pragma unroll
            for (int r = 0; r < 4; r++) {
                int rowi = ob + i2 * 16 + q4 * 4 + r;
                int e = j * 16 + ln;
                float den = denom2[rowi] + denom2[128 + rowi];
                den = fmaxf(den, 1e-6f);
                float val = oacc[i2][j][r] / den;
                attnb[(size_t)(c * CHUNK + rowi) * HIDDEN + h * HD + e] = f2bf(val);
            }
}

// ---------------------------------------------------------------------------
// Kernel 4: out = attn @ Wo^T. A = attnb (bf16), B = Wo (fp32 -> bf16).
// grid (8, 16). fp32 output to d_out.
// ---------------------------------------------------------------------------
__global__ __launch_bounds__(256, 2)
void out_gemm(const u16* __restrict__ attn, const float* __restrict__ Wo,
              float* __restrict__ out)
{
    __shared__ u16 As[128 * 72];
    __shared__ u16 Bs[128 * 72];
    const int bn = blockIdx.x, bm = blockIdx.y;
    const int n0 = bn * 128, m0 = bm * 128;
    const int t = threadIdx.x;
    const int lane = t & 63, wave = t >> 6;
    const int ln = lane & 15, q4 = lane >> 4;
    const int wm = (wave >> 1) * 64, wn = (wave & 1) * 64;
    const int srow = t >> 1, sc = (t & 1) * 32;

    floatx4 acc[4][4];
#pragma unroll
    for (int i = 0; i < 4; i++)
#pragma unroll
        for (int j = 0; j < 4; j++) acc[i][j] = (floatx4)0.0f;

    for (int k0 = 0; k0 < HIDDEN; k0 += 64) {
        const ushortx8* ga = (const ushortx8*)(attn + (size_t)(m0 + srow) * HIDDEN + k0 + sc);
        const float4* gb = (const float4*)(Wo + (size_t)(n0 + srow) * HIDDEN + k0 + sc);
        ushortx8 av[4];
        float4 bv[8];
#pragma unroll
        for (int i = 0; i < 4; i++) av[i] = ga[i];
#pragma unroll
        for (int i = 0; i < 8; i++) bv[i] = gb[i];
        __syncthreads();
        u16* pa = &As[srow * 72 + sc];
        u16* pb = &Bs[srow * 72 + sc];
#pragma unroll
        for (int i = 0; i < 4; i++) *(ushortx8*)(pa + i * 8) = av[i];
#pragma unroll
        for (int i = 0; i < 8; i++) {
            ushortx4 ub = { f2bf(bv[i].x), f2bf(bv[i].y), f2bf(bv[i].z), f2bf(bv[i].w) };
            *(ushortx4*)(pb + i * 4) = ub;
        }
        __syncthreads();
#pragma unroll
        for (int s = 0; s < 2; s++) {
            short8 af[4], bfr[4];
#pragma unroll
            for (int i = 0; i < 4; i++)
                af[i] = *(const short8*)&As[(wm + i * 16 + ln) * 72 + s * 32 + q4 * 8];
#pragma unroll
            for (int j = 0; j < 4; j++)
                bfr[j] = *(const short8*)&Bs[(wn + j * 16 + ln) * 72 + s * 32 + q4 * 8];
#pragma unroll
            for (int i = 0; i < 4; i++)
#pragma unroll
                for (int j = 0; j < 4; j++)
                    acc[i][j] = __builtin_amdgcn_mfma_f32_16x16x32_bf16(af[i], bfr[j], acc[i][j], 0, 0, 0);
        }
    }
#pragma unroll
    for (int i = 0; i < 4; i++)
#pragma unroll
        for (int j = 0; j < 4; j++)
#pragma unroll
            for (int r = 0; r < 4; r++) {
                int m = m0 + wm + i * 16 + q4 * 4 + r;
                int n = n0 + wn + j * 16 + ln;
                out[(size_t)m * HIDDEN + n] = acc[i][j][r];
            }
}

// ---------------------------------------------------------------------------
// Workspace layout (bytes):
//   qb    @ 0        4 MB  (bf16 [2048][1024])
//   kb    @ 4 MB     4 MB
//   vb    @ 8 MB     4 MB
//   attnb @ 12 MB    4 MB
//   S_ws  @ 16 MB    4 MB  (fp32 S^T per (h,c): [16][16][64*64])
//   ksum  @ 20 MB    256 KB
// total 20.25 MB
// ---------------------------------------------------------------------------
extern "C" void kernel_launch(void* const* d_in, const int* in_sizes, int n_in,
                              void* d_out, int out_size, void* d_ws, size_t ws_size,
                              hipStream_t stream)
{
    const float* x  = (const float*)d_in[0];
    const float* Wq = (const float*)d_in[1];
    const float* Wk = (const float*)d_in[2];
    const float* Wv = (const float*)d_in[3];
    const float* Wo = (const float*)d_in[4];
    float* out = (float*)d_out;

    char* ws = (char*)d_ws;
    const size_t MB = 1024 * 1024;
    u16* qb    = (u16*)(ws + 0 * MB);
    u16* kb    = (u16*)(ws + 4 * MB);
    u16* vb    = (u16*)(ws + 8 * MB);
    u16* attnb = (u16*)(ws + 12 * MB);
    float* S_ws    = (float*)(ws + 16 * MB);
    float* ksum_ws = (float*)(ws + 20 * MB);

    qkv_gemm<<<dim3(24, 16), 256, 0, stream>>>(x, Wq, Wk, Wv, qb, kb, vb);
    chunk_stats<<<dim3(NCHUNK, NH), 256, 0, stream>>>(kb, vb, S_ws, ksum_ws);
    attn_out<<<dim3(NCHUNK, NH), 256, 0, stream>>>(qb, kb, vb, S_ws, ksum_ws, attnb);
    out_gemm<<<dim3(8, 16), 256, 0, stream>>>(attnb, Wo, out);
}

// Round 2
// 137.498 us; speedup vs baseline: 1.6515x; 1.6515x over previous
//
#include <hip/hip_runtime.h>
#include <hip/hip_bf16.h>

typedef __attribute__((ext_vector_type(8))) short short8;
typedef __attribute__((ext_vector_type(4))) float floatx4;
typedef __attribute__((ext_vector_type(8))) unsigned short ushortx8;
typedef __attribute__((ext_vector_type(4))) unsigned short ushortx4;
typedef unsigned short u16;

#define HIDDEN 1024
#define NH 16
#define HD 64
#define SEQ 2048
#define CHUNK 128
#define NCHUNK (SEQ / CHUNK)  // 16

__device__ __forceinline__ u16 f2bf(float f) {
    union { float f; unsigned u; } v; v.f = f;
    unsigned r = v.u + 0x7fffu + ((v.u >> 16) & 1u);
    return (u16)(r >> 16);
}
__device__ __forceinline__ float bf2f(u16 u) {
    union { unsigned u; float f; } v; v.u = ((unsigned)u) << 16;
    return v.f;
}

// async 16B global->LDS (wave-uniform base + lane*16; LDS layout must be
// lane-linear — no padding. Read-side conflicts handled by XOR chunk swizzle.)
__device__ __forceinline__ void gl_lds16(const u16* g, u16* l) {
    __builtin_amdgcn_global_load_lds(
        (const __attribute__((address_space(1))) void*)g,
        (__attribute__((address_space(3))) void*)l,
        16, 0, 0);
}

// ---------------------------------------------------------------------------
// Kernel 0: one-shot fp32 -> bf16 conversion of x, Wq|Wk|Wv (fused), Wo.
// Memory-bound: 24 MB read + 12 MB write. Removes all f2bf from GEMM loops
// and enables global_load_lds staging.
// ---------------------------------------------------------------------------
__global__ __launch_bounds__(256)
void convert_all(const float* __restrict__ x,  const float* __restrict__ Wq,
                 const float* __restrict__ Wk, const float* __restrict__ Wv,
                 const float* __restrict__ Wo,
                 u16* __restrict__ xb, u16* __restrict__ Wb, u16* __restrict__ Wob)
{
    const int total4 = 1572864;  // 6M floats / 4
    for (int idx = blockIdx.x * 256 + threadIdx.x; idx < total4; idx += gridDim.x * 256) {
        const float4* src; u16* dst; int off;
        if (idx < 524288)       { src = (const float4*)x;  dst = xb;            off = idx; }
        else if (idx < 786432)  { src = (const float4*)Wq; dst = Wb;            off = idx - 524288; }
        else if (idx < 1048576) { src = (const float4*)Wk; dst = Wb + 1048576;  off = idx - 786432; }
        else if (idx < 1310720) { src = (const float4*)Wv; dst = Wb + 2097152;  off = idx - 1048576; }
        else                    { src = (const float4*)Wo; dst = Wob;           off = idx - 1310720; }
        float4 v = src[off];
        ushortx4 u = { f2bf(v.x), f2bf(v.y), f2bf(v.z), f2bf(v.w) };
        *(ushortx4*)(dst + (size_t)off * 4) = u;
    }
}

// ---------------------------------------------------------------------------
// m97-style bf16 GEMM: C[m][n] = sum_k A[m][k]*B[n][k]  (B row-major = B^T).
// TM x 128 tile, BK=64, 4 waves. global_load_lds dwordx4 staging with XOR
// chunk swizzle: LDS(r, c') holds global chunk c = c' ^ (r&7)  (16B chunks),
// making ds_read_b128 fragment reads 2-way (free) instead of 16-way.
// ELU: apply elu(.)+1 to output cols < 2048 (q,k of the fused qkv buffer).
// ---------------------------------------------------------------------------
template<int TM, bool ELU, typename OutT>
__global__ __launch_bounds__(256, 2)
void gemm_m97(const u16* __restrict__ A, const u16* __restrict__ Bm,
              OutT* __restrict__ C, const int K, const int ldc)
{
    constexpr int FI = TM / 32;               // A-frag rows per wave
    __shared__ u16 As[TM * 64];               // no padding (DMA constraint)
    __shared__ u16 Bs[128 * 64];
    const int m0 = blockIdx.y * TM, n0 = blockIdx.x * 128;
    const int t = threadIdx.x;
    const int lane = t & 63, wave = t >> 6;
    const int ln = lane & 15, q4 = lane >> 4;
    const int wm = (wave >> 1) * (TM / 2);
    const int wn = (wave & 1) * 64;
    const int r_in = t >> 3;                              // staging row 0..31
    const int csw = (((t & 7) ^ (r_in & 7)) << 3);        // swizzled k-chunk (elems)

    const u16* Ag = A + (size_t)(m0 + r_in) * K + csw;
    const u16* Bg = Bm + (size_t)(n0 + r_in) * K + csw;

    floatx4 acc[FI][4];
#pragma unroll
    for (int i = 0; i < FI; i++)
#pragma unroll
        for (int j = 0; j < 4; j++) acc[i][j] = (floatx4)0.0f;

    for (int k0 = 0; k0 < K; k0 += 64) {
        if (k0) __syncthreads();              // LDS reads of prev iter done
#pragma unroll
        for (int i = 0; i < FI; i++)
            gl_lds16(Ag + (size_t)i * 32 * K, &As[i * 2048 + t * 8]);
#pragma unroll
        for (int i = 0; i < 4; i++)
            gl_lds16(Bg + (size_t)i * 32 * K, &Bs[i * 2048 + t * 8]);
        Ag += 64; Bg += 64;
        __syncthreads();                      // drains vmcnt(0): tiles visible
#pragma unroll
        for (int s = 0; s < 2; s++) {
            const int rc = (((s * 4 + q4) ^ (ln & 7)) << 3);
            short8 af[FI], bfr[4];
#pragma unroll
            for (int i = 0; i < FI; i++)
                af[i] = *(const short8*)&As[(wm + i * 16 + ln) * 64 + rc];
#pragma unroll
            for (int j = 0; j < 4; j++)
                bfr[j] = *(const short8*)&Bs[(wn + j * 16 + ln) * 64 + rc];
#pragma unroll
            for (int i = 0; i < FI; i++)
#pragma unroll
                for (int j = 0; j < 4; j++)
                    acc[i][j] = __builtin_amdgcn_mfma_f32_16x16x32_bf16(af[i], bfr[j], acc[i][j], 0, 0, 0);
        }
    }
    // C/D layout: col = lane&15, row = (lane>>4)*4 + reg
#pragma unroll
    for (int i = 0; i < FI; i++)
#pragma unroll
        for (int j = 0; j < 4; j++)
#pragma unroll
            for (int rr = 0; rr < 4; rr++) {
                int m = m0 + wm + i * 16 + q4 * 4 + rr;
                int n = n0 + wn + j * 16 + ln;
                float v = acc[i][j][rr];
                if (ELU && n < 2048) v = (v > 0.f) ? (v + 1.f) : __expf(v);
                if constexpr (sizeof(OutT) == 2) C[(size_t)m * ldc + n] = f2bf(v);
                else                             C[(size_t)m * ldc + n] = v;
            }
}

// ---------------------------------------------------------------------------
// Kernel 2: per-(chunk,head) state S_c[d][e] = sum_j K[j][d]*V[j][e] via MFMA.
// qkv buffer layout: row l (stride 3072): [q 0..1023 | k 1024..2047 | v 2048..3071]
// Stores S^T (e-major) + ksum[d]. grid (16,16).
// ---------------------------------------------------------------------------
__global__ __launch_bounds__(256, 2)
void chunk_stats(const u16* __restrict__ qkv,
                 float* __restrict__ S_ws, float* __restrict__ ksum_ws)
{
    __shared__ u16 kT[64 * 136];
    __shared__ u16 vT[64 * 136];
    const int c = blockIdx.x, h = blockIdx.y;
    const int t = threadIdx.x;
    const int lane = t & 63, wave = t >> 6;
    const int ln = lane & 15, q4 = lane >> 4;
    {
        const int row = t >> 1, sc = (t & 1) * 32;
        const size_t gk = (size_t)(c * CHUNK + row) * 3072 + 1024 + h * HD + sc;
        u16 kr[32], vr[32];
#pragma unroll
        for (int i = 0; i < 4; i++) {
            *(ushortx8*)&kr[i * 8] = *(const ushortx8*)(qkv + gk + i * 8);
            *(ushortx8*)&vr[i * 8] = *(const ushortx8*)(qkv + gk + 1024 + i * 8);
        }
#pragma unroll
        for (int j = 0; j < 32; j++) {
            kT[(sc + j) * 136 + row] = kr[j];
            vT[(sc + j) * 136 + row] = vr[j];
        }
    }
    __syncthreads();
    floatx4 sacc[4];
#pragma unroll
    for (int j = 0; j < 4; j++) sacc[j] = (floatx4)0.0f;
#pragma unroll
    for (int ks = 0; ks < 4; ks++) {
        short8 af = *(const short8*)&kT[(wave * 16 + ln) * 136 + ks * 32 + q4 * 8];
#pragma unroll
        for (int j = 0; j < 4; j++) {
            short8 bfr = *(const short8*)&vT[(j * 16 + ln) * 136 + ks * 32 + q4 * 8];
            sacc[j] = __builtin_amdgcn_mfma_f32_16x16x32_bf16(af, bfr, sacc[j], 0, 0, 0);
        }
    }
    float* Sp = S_ws + ((size_t)(h * NCHUNK + c) << 12);
#pragma unroll
    for (int j = 0; j < 4; j++)
#pragma unroll
        for (int r = 0; r < 4; r++) {
            int d = wave * 16 + q4 * 4 + r;
            int e = j * 16 + ln;
            Sp[e * 64 + d] = sacc[j][r];  // S^T layout [e][d]
        }
    if (t < 64) {
        float s = 0.f;
#pragma unroll
        for (int j = 0; j < 128; j++) s += bf2f(kT[t * 136 + j]);
        ksum_ws[(h * NCHUNK + c) * 64 + t] = s;
    }
}

// ---------------------------------------------------------------------------
// Kernel 3: attention output per (chunk, head).
//   KV_prefix = sum_{c'<c} S_c'  (on-the-fly, L2-resident)
//   P = QK^T (causal-masked), denom = rowsum(P) + q.kpref
//   O = P V + Q KV_prefix; attn = O / denom
// grid (16,16).
// ---------------------------------------------------------------------------
__global__ __launch_bounds__(256, 1)
void attn_out(const u16* __restrict__ qkv, const float* __restrict__ S_ws,
              const float* __restrict__ ksum_ws, u16* __restrict__ attnb)
{
    __shared__ __align__(16) u16 smem[32384];  // 64768 B
    u16* q_l   = smem;          // [128][72]
    u16* k_l   = smem + 9216;   // [128][72]
    u16* P_l   = smem;          // [128][136] — aliases q_l+k_l after both dead
    u16* vT_l  = smem + 18432;  // [64][136]  V^T
    u16* kvT_l = smem + 27136;  // [64][72]   KV_prefix^T (bf16)
    float* kpref  = (float*)(smem + 31744);  // [64]
    float* denom2 = kpref + 64;              // [2][128]

    const int c = blockIdx.x, h = blockIdx.y;
    const int t = threadIdx.x;
    const int lane = t & 63, wave = t >> 6;
    const int ln = lane & 15, q4 = lane >> 4;

    // --- stage q,k row-major; v transposed ---
    {
        const int row = t >> 1, sc = (t & 1) * 32;
        const size_t gq = (size_t)(c * CHUNK + row) * 3072 + h * HD + sc;
#pragma unroll
        for (int i = 0; i < 4; i++) {
            *(ushortx8*)&q_l[row * 72 + sc + i * 8] = *(const ushortx8*)(qkv + gq + i * 8);
            *(ushortx8*)&k_l[row * 72 + sc + i * 8] = *(const ushortx8*)(qkv + gq + 1024 + i * 8);
        }
        u16 vr[32];
#pragma unroll
        for (int i = 0; i < 4; i++) *(ushortx8*)&vr[i * 8] = *(const ushortx8*)(qkv + gq + 2048 + i * 8);
#pragma unroll
        for (int j = 0; j < 32; j++) vT_l[(sc + j) * 136 + row] = vr[j];
    }
    // --- KV prefix accumulation (thread owns e = t>>2, 16 d's) ---
    {
        const int e = t >> 2, db = (t & 3) * 16;
        float kv[16];
#pragma unroll
        for (int i = 0; i < 16; i++) kv[i] = 0.f;
        for (int cp = 0; cp < c; cp++) {
            const float* Sp = S_ws + ((size_t)(h * NCHUNK + cp) << 12) + e * 64 + db;
#pragma unroll
            for (int g = 0; g < 4; g++) {
                float4 s4 = *(const float4*)(Sp + g * 4);
                kv[g * 4 + 0] += s4.x; kv[g * 4 + 1] += s4.y;
                kv[g * 4 + 2] += s4.z; kv[g * 4 + 3] += s4.w;
            }
        }
#pragma unroll
        for (int g = 0; g < 4; g++) {
            ushortx4 u = { f2bf(kv[g * 4 + 0]), f2bf(kv[g * 4 + 1]),
                           f2bf(kv[g * 4 + 2]), f2bf(kv[g * 4 + 3]) };
            *(ushortx4*)&kvT_l[e * 72 + db + g * 4] = u;
        }
        if (t < 64) {
            float s = 0.f;
            for (int cp = 0; cp < c; cp++) s += ksum_ws[(h * NCHUNK + cp) * 64 + t];
            kpref[t] = s;
        }
    }
    __syncthreads();

    // --- P = QK^T : wave quadrant (pm, pn), 64x64, K=64 ---
    const int pm = (wave >> 1) * 64, pn = (wave & 1) * 64;
    floatx4 pacc[4][4];
#pragma unroll
    for (int i = 0; i < 4; i++)
#pragma unroll
        for (int j = 0; j < 4; j++) pacc[i][j] = (floatx4)0.0f;
#pragma unroll
    for (int s = 0; s < 2; s++) {
        short8 af[4], bfr[4];
#pragma unroll
        for (int i = 0; i < 4; i++)
            af[i] = *(const short8*)&q_l[(pm + i * 16 + ln) * 72 + s * 32 + q4 * 8];
#pragma unroll
        for (int j = 0; j < 4; j++)
            bfr[j] = *(const short8*)&k_l[(pn + j * 16 + ln) * 72 + s * 32 + q4 * 8];
#pragma unroll
        for (int i = 0; i < 4; i++)
#pragma unroll
            for (int j = 0; j < 4; j++)
                pacc[i][j] = __builtin_amdgcn_mfma_f32_16x16x32_bf16(af[i], bfr[j], pacc[i][j], 0, 0, 0);
    }
    // --- causal mask + rowsum (denominator part) ---
#pragma unroll
    for (int i = 0; i < 4; i++)
#pragma unroll
        for (int r = 0; r < 4; r++) {
            int rowi = pm + i * 16 + q4 * 4 + r;
            float rs = 0.f;
#pragma unroll
            for (int j = 0; j < 4; j++) {
                int col = pn + j * 16 + ln;
                float p = pacc[i][j][r];
                if (col > rowi) p = 0.f;
                pacc[i][j][r] = p;
                rs += p;
            }
#pragma unroll
            for (int off = 1; off < 16; off <<= 1) rs += __shfl_xor(rs, off, 64);
            if (ln == 0) denom2[(wave & 1) * 128 + rowi] = rs;
        }
    // --- O_inter = Q @ KV_prefix : wave rows ob..ob+31, cols 0..63 ---
    const int ob = wave * 32;
    floatx4 oacc[2][4];
#pragma unroll
    for (int i = 0; i < 2; i++)
#pragma unroll
        for (int j = 0; j < 4; j++) oacc[i][j] = (floatx4)0.0f;
#pragma unroll
    for (int s = 0; s < 2; s++) {
        short8 af[2], bfr[4];
#pragma unroll
        for (int i2 = 0; i2 < 2; i2++)
            af[i2] = *(const short8*)&q_l[(ob + i2 * 16 + ln) * 72 + s * 32 + q4 * 8];
#pragma unroll
        for (int j = 0; j < 4; j++)
            bfr[j] = *(const short8*)&kvT_l[(j * 16 + ln) * 72 + s * 32 + q4 * 8];
#pragma unroll
        for (int i2 = 0; i2 < 2; i2++)
#pragma unroll
            for (int j = 0; j < 4; j++)
                oacc[i2][j] = __builtin_amdgcn_mfma_f32_16x16x32_bf16(af[i2], bfr[j], oacc[i2][j], 0, 0, 0);
    }
    __syncthreads();  // denom2 rowsums visible; all q_l/k_l MFMA reads done
    // --- denominator inter part: q_i . kpref ---
    if (t < 128) {
        float s = 0.f;
#pragma unroll
        for (int d = 0; d < 64; d++) s += bf2f(q_l[t * 72 + d]) * kpref[d];
        denom2[t] += s;  // slot [0][t]
    }
    __syncthreads();  // q_l reads done; safe to overwrite with P
    // --- write masked P (bf16) into aliased LDS ---
#pragma unroll
    for (int i = 0; i < 4; i++)
#pragma unroll
        for (int j = 0; j < 4; j++)
#pragma unroll
            for (int r = 0; r < 4; r++) {
                int rowi = pm + i * 16 + q4 * 4 + r;
                int col = pn + j * 16 + ln;
                P_l[rowi * 136 + col] = f2bf(pacc[i][j][r]);
            }
    __syncthreads();
    // --- O_intra = P @ V : K=128, causal skip (ks <= wave) ---
    for (int ks = 0; ks <= wave; ks++) {
        short8 af[2], bfr[4];
#pragma unroll
        for (int i2 = 0; i2 < 2; i2++)
            af[i2] = *(const short8*)&P_l[(ob + i2 * 16 + ln) * 136 + ks * 32 + q4 * 8];
#pragma unroll
        for (int j = 0; j < 4; j++)
            bfr[j] = *(const short8*)&vT_l[(j * 16 + ln) * 136 + ks * 32 + q4 * 8];
#pragma unroll
        for (int i2 = 0; i2 < 2; i2++)
#pragma unroll
            for (int j = 0; j < 4; j++)
                oacc[i2][j] = __builtin_amdgcn_mfma_f32_16x16x32_bf16(af[i2], bfr[j], oacc[i2][j], 0, 0, 0);
    }
    // --- normalize + store ---
#pragma unroll
    for (int i2 = 0; i2 < 2; i2++)
#pragma unroll
        for (int j = 0; j < 4; j++)
#pragma unroll
            for (int r = 0; r < 4; r++) {
                int rowi = ob + i2 * 16 + q4 * 4 + r;
                int e = j * 16 + ln;
                float den = denom2[rowi] + denom2[128 + rowi];
                den = fmaxf(den, 1e-6f);
                float val = oacc[i2][j][r] / den;
                attnb[(size_t)(c * CHUNK + rowi) * HIDDEN + h * HD + e] = f2bf(val);
            }
}

// ---------------------------------------------------------------------------
// Workspace layout (24 MB, time-aliased):
//   qkvb  @  0 MB  12 MB  bf16 [2048][3072] = q|k|v fused (written d2, read d3,d4)
//   xb    @ 12 MB   4 MB  bf16 x (written d1, read d2)
//   attnb @ 12 MB   4 MB  aliases xb (written d4, read d5 — xb dead)
//   Wb    @ 16 MB   6 MB  bf16 Wq|Wk|Wv rows (written d1, read d2)
//   S_ws  @ 16 MB   4 MB  aliases Wb (written d3 — Wb dead)
//   ksum  @ 20 MB 256 KB  aliases Wb tail
//   Wob   @ 22 MB   2 MB  bf16 Wo (written d1, read d5)
// ---------------------------------------------------------------------------
extern "C" void kernel_launch(void* const* d_in, const int* in_sizes, int n_in,
                              void* d_out, int out_size, void* d_ws, size_t ws_size,
                              hipStream_t stream)
{
    const float* x  = (const float*)d_in[0];
    const float* Wq = (const float*)d_in[1];
    const float* Wk = (const float*)d_in[2];
    const float* Wv = (const float*)d_in[3];
    const float* Wo = (const float*)d_in[4];
    float* out = (float*)d_out;

    char* ws = (char*)d_ws;
    const size_t MB = 1024 * 1024;
    u16* qkvb  = (u16*)(ws);
    u16* xb    = (u16*)(ws + 12 * MB);
    u16* attnb = (u16*)(ws + 12 * MB);
    u16* Wb    = (u16*)(ws + 16 * MB);
    float* S_ws    = (float*)(ws + 16 * MB);
    float* ksum_ws = (float*)(ws + 20 * MB);
    u16* Wob   = (u16*)(ws + 22 * MB);

    convert_all<<<2048, 256, 0, stream>>>(x, Wq, Wk, Wv, Wo, xb, Wb, Wob);
    gemm_m97<128, true, u16><<<dim3(24, 16), 256, 0, stream>>>(xb, Wb, qkvb, 1024, 3072);
    chunk_stats<<<dim3(NCHUNK, NH), 256, 0, stream>>>(qkvb, S_ws, ksum_ws);
    attn_out<<<dim3(NCHUNK, NH), 256, 0, stream>>>(qkvb, S_ws, ksum_ws, attnb);
    gemm_m97<64, false, float><<<dim3(8, 32), 256, 0, stream>>>(attnb, Wob, out, 1024, 1024);
}

// Round 3
// 130.068 us; speedup vs baseline: 1.7459x; 1.0571x over previous
//
#include <hip/hip_runtime.h>
#include <hip/hip_bf16.h>

typedef __attribute__((ext_vector_type(8))) short short8;
typedef __attribute__((ext_vector_type(4))) float floatx4;
typedef __attribute__((ext_vector_type(8))) unsigned short ushortx8;
typedef __attribute__((ext_vector_type(4))) unsigned short ushortx4;
typedef unsigned short u16;

#define HIDDEN 1024
#define NH 16
#define HD 64
#define SEQ 2048
#define CHUNK 128
#define NCHUNK (SEQ / CHUNK)  // 16

__device__ __forceinline__ u16 f2bf(float f) {
    union { float f; unsigned u; } v; v.f = f;
    unsigned r = v.u + 0x7fffu + ((v.u >> 16) & 1u);
    return (u16)(r >> 16);
}
__device__ __forceinline__ float bf2f(u16 u) {
    union { unsigned u; float f; } v; v.u = ((unsigned)u) << 16;
    return v.f;
}

// async 16B global->LDS. LDS dest is wave-uniform base + lane*16 (no pad);
// read-side bank conflicts handled by XOR chunk swizzle on the GLOBAL addr.
__device__ __forceinline__ void gl_lds16(const u16* g, u16* l) {
    __builtin_amdgcn_global_load_lds(
        (const __attribute__((address_space(1))) void*)g,
        (__attribute__((address_space(3))) void*)l,
        16, 0, 0);
}

// ---------------------------------------------------------------------------
// Kernel 0: fp32 -> bf16 of x, Wq|Wk|Wv (fused rows), Wo. ~36 MB traffic.
// ---------------------------------------------------------------------------
__global__ __launch_bounds__(256)
void convert_all(const float* __restrict__ x,  const float* __restrict__ Wq,
                 const float* __restrict__ Wk, const float* __restrict__ Wv,
                 const float* __restrict__ Wo,
                 u16* __restrict__ xb, u16* __restrict__ Wb, u16* __restrict__ Wob)
{
    const int total4 = 1572864;  // 6M floats / 4
    for (int idx = blockIdx.x * 256 + threadIdx.x; idx < total4; idx += gridDim.x * 256) {
        const float4* src; u16* dst; int off;
        if (idx < 524288)       { src = (const float4*)x;  dst = xb;            off = idx; }
        else if (idx < 786432)  { src = (const float4*)Wq; dst = Wb;            off = idx - 524288; }
        else if (idx < 1048576) { src = (const float4*)Wk; dst = Wb + 1048576;  off = idx - 786432; }
        else if (idx < 1310720) { src = (const float4*)Wv; dst = Wb + 2097152;  off = idx - 1048576; }
        else                    { src = (const float4*)Wo; dst = Wob;           off = idx - 1310720; }
        float4 v = src[off];
        ushortx4 u = { f2bf(v.x), f2bf(v.y), f2bf(v.z), f2bf(v.w) };
        *(ushortx4*)(dst + (size_t)off * 4) = u;
    }
}

// ---------------------------------------------------------------------------
// Kernel 1: fused QKV GEMM, 64x128 tile (768 blocks = 3/CU), BK=64, m97-style
// global_load_lds staging + XOR swizzle. Epilogue:
//   q (cols 0..1023):    elu+1, row-major into qkb[:, 0:1024]
//   k (cols 1024..2047): elu+1, row-major into qkb[:, 1024:2048] AND kT_b[h][d][l]
//   v (cols 2048..3071): vT_b[h][e][l] ONLY (nothing needs v row-major)
// Transposed stores pack the contiguous m-register axis -> ushortx4.
// ---------------------------------------------------------------------------
__global__ __launch_bounds__(256, 3)
void qkv_gemm64(const u16* __restrict__ A, const u16* __restrict__ Bm,
                u16* __restrict__ qkb, u16* __restrict__ kT_b, u16* __restrict__ vT_b)
{
    __shared__ u16 As[64 * 64];
    __shared__ u16 Bs[128 * 64];
    const int n0 = blockIdx.x * 128, m0 = blockIdx.y * 64;
    const int t = threadIdx.x;
    const int lane = t & 63, wave = t >> 6;
    const int ln = lane & 15, q4 = lane >> 4;
    const int wm = (wave >> 1) * 32, wn = (wave & 1) * 64;
    const int r_in = t >> 3;
    const int csw = (((t & 7) ^ (r_in & 7)) << 3);

    const u16* Ag = A + (size_t)(m0 + r_in) * 1024 + csw;
    const u16* Bg = Bm + (size_t)(n0 + r_in) * 1024 + csw;

    floatx4 acc[2][4];
#pragma unroll
    for (int i = 0; i < 2; i++)
#pragma unroll
        for (int j = 0; j < 4; j++) acc[i][j] = (floatx4)0.0f;

    for (int k0 = 0; k0 < 1024; k0 += 64) {
        if (k0) __syncthreads();
        gl_lds16(Ag, &As[t * 8]);
        gl_lds16(Ag + 32 * 1024, &As[2048 + t * 8]);
#pragma unroll
        for (int i = 0; i < 4; i++)
            gl_lds16(Bg + (size_t)i * 32 * 1024, &Bs[i * 2048 + t * 8]);
        Ag += 64; Bg += 64;
        __syncthreads();
#pragma unroll
        for (int s = 0; s < 2; s++) {
            const int rc = (((s * 4 + q4) ^ (ln & 7)) << 3);
            short8 af[2], bfr[4];
#pragma unroll
            for (int i = 0; i < 2; i++)
                af[i] = *(const short8*)&As[(wm + i * 16 + ln) * 64 + rc];
#pragma unroll
            for (int j = 0; j < 4; j++)
                bfr[j] = *(const short8*)&Bs[(wn + j * 16 + ln) * 64 + rc];
#pragma unroll
            for (int i = 0; i < 2; i++)
#pragma unroll
                for (int j = 0; j < 4; j++)
                    acc[i][j] = __builtin_amdgcn_mfma_f32_16x16x32_bf16(af[i], bfr[j], acc[i][j], 0, 0, 0);
        }
    }
    const int grp = n0 >> 10;  // 0=q 1=k 2=v (block-uniform)
#pragma unroll
    for (int i = 0; i < 2; i++)
#pragma unroll
        for (int j = 0; j < 4; j++) {
            const int mb = m0 + wm + i * 16 + q4 * 4;
            const int n = n0 + wn + j * 16 + ln;
            const int nh = n & 1023, h = nh >> 6, e = nh & 63;
            float vals[4];
#pragma unroll
            for (int r = 0; r < 4; r++) {
                float v = acc[i][j][r];
                if (grp < 2) v = (v > 0.f) ? (v + 1.f) : __expf(v);
                vals[r] = v;
            }
            if (grp == 0) {
#pragma unroll
                for (int r = 0; r < 4; r++) qkb[(size_t)(mb + r) * 2048 + nh] = f2bf(vals[r]);
            } else if (grp == 1) {
#pragma unroll
                for (int r = 0; r < 4; r++) qkb[(size_t)(mb + r) * 2048 + 1024 + nh] = f2bf(vals[r]);
                ushortx4 u = { f2bf(vals[0]), f2bf(vals[1]), f2bf(vals[2]), f2bf(vals[3]) };
                *(ushortx4*)&kT_b[(size_t)(h * 64 + e) * 2048 + mb] = u;
            } else {
                ushortx4 u = { f2bf(vals[0]), f2bf(vals[1]), f2bf(vals[2]), f2bf(vals[3]) };
                *(ushortx4*)&vT_b[(size_t)(h * 64 + e) * 2048 + mb] = u;
            }
        }
}

// ---------------------------------------------------------------------------
// Kernel 2: S_c[d][e] = sum_l K[l][d] V[l][e] per (c,h) via MFMA, staged
// entirely with global_load_lds from kT_b/vT_b (reduction axis l contig).
// Stores S^T [e][d] + ksum[d]. grid (16,16).
// ---------------------------------------------------------------------------
__global__ __launch_bounds__(256, 2)
void chunk_stats2(const u16* __restrict__ kT_b, const u16* __restrict__ vT_b,
                  float* __restrict__ S_ws, float* __restrict__ ksum_ws)
{
    __shared__ u16 kT_l[64 * 128];
    __shared__ u16 vT_l[64 * 128];
    const int c = blockIdx.x, h = blockIdx.y;
    const int t = threadIdx.x;
    const int lane = t & 63, w = t >> 6;
    const int ln = lane & 15, q4 = lane >> 4;
#pragma unroll
    for (int i = 0; i < 4; i++) {
        const int d0 = w * 16 + i * 4 + (lane >> 4);
        const int cc = lane & 15;
        const size_t gsrc = (size_t)(h * 64 + d0) * 2048 + c * 128 + ((cc ^ (d0 & 7)) << 3);
        gl_lds16(kT_b + gsrc, &kT_l[(w * 16 + i * 4) * 128 + lane * 8]);
        gl_lds16(vT_b + gsrc, &vT_l[(w * 16 + i * 4) * 128 + lane * 8]);
    }
    __syncthreads();
    floatx4 sacc[4];
#pragma unroll
    for (int j = 0; j < 4; j++) sacc[j] = (floatx4)0.0f;
#pragma unroll
    for (int ks = 0; ks < 4; ks++) {
        const int rc = (((ks * 4 + q4) ^ (ln & 7)) << 3);
        short8 af = *(const short8*)&kT_l[(w * 16 + ln) * 128 + rc];
#pragma unroll
        for (int j = 0; j < 4; j++) {
            short8 bfr = *(const short8*)&vT_l[(j * 16 + ln) * 128 + rc];
            sacc[j] = __builtin_amdgcn_mfma_f32_16x16x32_bf16(af, bfr, sacc[j], 0, 0, 0);
        }
    }
    float* Sp = S_ws + ((size_t)(h * NCHUNK + c) << 12);
#pragma unroll
    for (int j = 0; j < 4; j++)
#pragma unroll
        for (int r = 0; r < 4; r++) {
            int d = w * 16 + q4 * 4 + r;
            int e = j * 16 + ln;
            Sp[e * 64 + d] = sacc[j][r];  // S^T [e][d]
        }
    if (t < 64) {  // ksum[d]: row-sum of kT_l (swizzle permutes within row; sum invariant)
        float s = 0.f;
#pragma unroll
        for (int cc = 0; cc < 16; cc++) {
            ushortx8 v8 = *(const ushortx8*)&kT_l[t * 128 + cc * 8];
#pragma unroll
            for (int jj = 0; jj < 8; jj++) s += bf2f(v8[jj]);
        }
        ksum_ws[(h * NCHUNK + c) * 64 + t] = s;
    }
}

// ---------------------------------------------------------------------------
// Kernel 3: attention output per (c,h). All staging via global_load_lds:
// q_l/k_l [128][64] swizzled from qkb; vT_l [64][128] swizzled from vT_b.
// KV_prefix from S_ws. P round-trips LDS (aliased over q/k/kvT). grid (16,16).
// ---------------------------------------------------------------------------
__global__ __launch_bounds__(256, 1)
void attn_out2(const u16* __restrict__ qkb, const u16* __restrict__ vT_b,
               const float* __restrict__ S_ws, const float* __restrict__ ksum_ws,
               u16* __restrict__ attnb)
{
    __shared__ __align__(16) u16 smem[29824];  // 59648 B
    u16* q_l   = smem;           // [128][64] swizzled (8192)
    u16* k_l   = smem + 8192;    // [128][64] swizzled (8192)
    u16* kvT_l = smem + 16384;   // [64][72] padded, no swizzle (4608)
    u16* P_l   = smem;           // [128][136] (17408) — aliases q+k+kvT when dead
    u16* vT_l  = smem + 20992;   // [64][128] swizzled (8192)
    float* kpref  = (float*)(smem + 29184);  // [64]
    float* denom2 = kpref + 64;              // [2][128]

    const int c = blockIdx.x, h = blockIdx.y;
    const int t = threadIdx.x;
    const int lane = t & 63, w = t >> 6;
    const int ln = lane & 15, q4 = lane >> 4;

    // --- async staging: q,k rows (swizzled), vT rows (swizzled) ---
#pragma unroll
    for (int i = 0; i < 4; i++) {
        const int l = i * 32 + w * 8 + (lane >> 3);
        const int cc = lane & 7;
        const size_t gq = (size_t)(c * CHUNK + l) * 2048 + h * 64 + ((cc ^ (l & 7)) << 3);
        gl_lds16(qkb + gq,        &q_l[(i * 32 + w * 8) * 64 + lane * 8]);
        gl_lds16(qkb + gq + 1024, &k_l[(i * 32 + w * 8) * 64 + lane * 8]);
        const int d0 = w * 16 + i * 4 + (lane >> 4);
        const int cv = lane & 15;
        gl_lds16(vT_b + (size_t)(h * 64 + d0) * 2048 + c * 128 + ((cv ^ (d0 & 7)) << 3),
                 &vT_l[(w * 16 + i * 4) * 128 + lane * 8]);
    }
    // --- KV prefix (overlaps with DMA): thread owns e = t>>2, 16 d's ---
    {
        const int e = t >> 2, db = (t & 3) * 16;
        float kv[16];
#pragma unroll
        for (int i = 0; i < 16; i++) kv[i] = 0.f;
        for (int cp = 0; cp < c; cp++) {
            const float* Sp = S_ws + ((size_t)(h * NCHUNK + cp) << 12) + e * 64 + db;
#pragma unroll
            for (int g = 0; g < 4; g++) {
                float4 s4 = *(const float4*)(Sp + g * 4);
                kv[g * 4 + 0] += s4.x; kv[g * 4 + 1] += s4.y;
                kv[g * 4 + 2] += s4.z; kv[g * 4 + 3] += s4.w;
            }
        }
#pragma unroll
        for (int g = 0; g < 4; g++) {
            ushortx4 u = { f2bf(kv[g * 4 + 0]), f2bf(kv[g * 4 + 1]),
                           f2bf(kv[g * 4 + 2]), f2bf(kv[g * 4 + 3]) };
            *(ushortx4*)&kvT_l[e * 72 + db + g * 4] = u;
        }
        if (t < 64) {
            float s = 0.f;
            for (int cp = 0; cp < c; cp++) s += ksum_ws[(h * NCHUNK + cp) * 64 + t];
            kpref[t] = s;
        }
    }
    __syncthreads();

    // --- P = QK^T : wave quadrant, 64x64, K=64 ---
    const int pm = (w >> 1) * 64, pn = (w & 1) * 64;
    floatx4 pacc[4][4];
#pragma unroll
    for (int i = 0; i < 4; i++)
#pragma unroll
        for (int j = 0; j < 4; j++) pacc[i][j] = (floatx4)0.0f;
#pragma unroll
    for (int s = 0; s < 2; s++) {
        const int rc = (((s * 4 + q4) ^ (ln & 7)) << 3);
        short8 af[4], bfr[4];
#pragma unroll
        for (int i = 0; i < 4; i++)
            af[i] = *(const short8*)&q_l[(pm + i * 16 + ln) * 64 + rc];
#pragma unroll
        for (int j = 0; j < 4; j++)
            bfr[j] = *(const short8*)&k_l[(pn + j * 16 + ln) * 64 + rc];
#pragma unroll
        for (int i = 0; i < 4; i++)
#pragma unroll
            for (int j = 0; j < 4; j++)
                pacc[i][j] = __builtin_amdgcn_mfma_f32_16x16x32_bf16(af[i], bfr[j], pacc[i][j], 0, 0, 0);
    }
    // --- causal mask + rowsum ---
#pragma unroll
    for (int i = 0; i < 4; i++)
#pragma unroll
        for (int r = 0; r < 4; r++) {
            int rowi = pm + i * 16 + q4 * 4 + r;
            float rs = 0.f;
#pragma unroll
            for (int j = 0; j < 4; j++) {
                int col = pn + j * 16 + ln;
                float p = pacc[i][j][r];
                if (col > rowi) p = 0.f;
                pacc[i][j][r] = p;
                rs += p;
            }
#pragma unroll
            for (int off = 1; off < 16; off <<= 1) rs += __shfl_xor(rs, off, 64);
            if (ln == 0) denom2[(w & 1) * 128 + rowi] = rs;
        }
    // --- O_inter = Q @ KV_prefix : wave rows ob..ob+31 ---
    const int ob = w * 32;
    floatx4 oacc[2][4];
#pragma unroll
    for (int i = 0; i < 2; i++)
#pragma unroll
        for (int j = 0; j < 4; j++) oacc[i][j] = (floatx4)0.0f;
#pragma unroll
    for (int s = 0; s < 2; s++) {
        const int rc = (((s * 4 + q4) ^ (ln & 7)) << 3);
        short8 af[2], bfr[4];
#pragma unroll
        for (int i2 = 0; i2 < 2; i2++)
            af[i2] = *(const short8*)&q_l[(ob + i2 * 16 + ln) * 64 + rc];
#pragma unroll
        for (int j = 0; j < 4; j++)
            bfr[j] = *(const short8*)&kvT_l[(j * 16 + ln) * 72 + s * 32 + q4 * 8];
#pragma unroll
        for (int i2 = 0; i2 < 2; i2++)
#pragma unroll
            for (int j = 0; j < 4; j++)
                oacc[i2][j] = __builtin_amdgcn_mfma_f32_16x16x32_bf16(af[i2], bfr[j], oacc[i2][j], 0, 0, 0);
    }
    __syncthreads();  // denom rowsums visible; q/k/kvT MFMA reads done
    // --- denominator inter: q_i . kpref (q_l is swizzled: walk chunks) ---
    if (t < 128) {
        float s = 0.f;
#pragma unroll
        for (int c8 = 0; c8 < 8; c8++) {
            ushortx8 v8 = *(const ushortx8*)&q_l[t * 64 + ((c8 ^ (t & 7)) << 3)];
#pragma unroll
            for (int jj = 0; jj < 8; jj++) s += bf2f(v8[jj]) * kpref[c8 * 8 + jj];
        }
        denom2[t] += s;
    }
    __syncthreads();  // q_l reads done; safe to overwrite with P
    // --- write masked P (bf16, unswizzled, pad 136) ---
#pragma unroll
    for (int i = 0; i < 4; i++)
#pragma unroll
        for (int j = 0; j < 4; j++)
#pragma unroll
            for (int r = 0; r < 4; r++) {
                int rowi = pm + i * 16 + q4 * 4 + r;
                int col = pn + j * 16 + ln;
                P_l[rowi * 136 + col] = f2bf(pacc[i][j][r]);
            }
    __syncthreads();
    // --- O_intra = P @ V : causal skip (ks <= wave) ---
    for (int ks = 0; ks <= w; ks++) {
        short8 af[2], bfr[4];
#pragma unroll
        for (int i2 = 0; i2 < 2; i2++)
            af[i2] = *(const short8*)&P_l[(ob + i2 * 16 + ln) * 136 + ks * 32 + q4 * 8];
        const int rc = (((ks * 4 + q4) ^ (ln & 7)) << 3);
#pragma unroll
        for (int j = 0; j < 4; j++)
            bfr[j] = *(const short8*)&vT_l[(j * 16 + ln) * 128 + rc];
#pragma unroll
        for (int i2 = 0; i2 < 2; i2++)
#pragma unroll
            for (int j = 0; j < 4; j++)
                oacc[i2][j] = __builtin_amdgcn_mfma_f32_16x16x32_bf16(af[i2], bfr[j], oacc[i2][j], 0, 0, 0);
    }
    // --- normalize + store ---
#pragma unroll
    for (int i2 = 0; i2 < 2; i2++)
#pragma unroll
        for (int j = 0; j < 4; j++)
#pragma unroll
            for (int r = 0; r < 4; r++) {
                int rowi = ob + i2 * 16 + q4 * 4 + r;
                int e = j * 16 + ln;
                float den = denom2[rowi] + denom2[128 + rowi];
                den = fmaxf(den, 1e-6f);
                float val = oacc[i2][j][r] / den;
                attnb[(size_t)(c * CHUNK + rowi) * HIDDEN + h * HD + e] = f2bf(val);
            }
}

// ---------------------------------------------------------------------------
// Kernel 4: out = attn @ Wo^T, 64x64 tile (512 blocks = 2/CU), fp32 out.
// ---------------------------------------------------------------------------
__global__ __launch_bounds__(256, 3)
void out_gemm64(const u16* __restrict__ A, const u16* __restrict__ Bm,
                float* __restrict__ out)
{
    __shared__ u16 As[64 * 64];
    __shared__ u16 Bs[64 * 64];
    const int n0 = blockIdx.x * 64, m0 = blockIdx.y * 64;
    const int t = threadIdx.x;
    const int lane = t & 63, wave = t >> 6;
    const int ln = lane & 15, q4 = lane >> 4;
    const int wm = (wave >> 1) * 32, wn = (wave & 1) * 32;
    const int r_in = t >> 3;
    const int csw = (((t & 7) ^ (r_in & 7)) << 3);

    const u16* Ag = A + (size_t)(m0 + r_in) * 1024 + csw;
    const u16* Bg = Bm + (size_t)(n0 + r_in) * 1024 + csw;

    floatx4 acc[2][2];
#pragma unroll
    for (int i = 0; i < 2; i++)
#pragma unroll
        for (int j = 0; j < 2; j++) acc[i][j] = (floatx4)0.0f;

    for (int k0 = 0; k0 < 1024; k0 += 64) {
        if (k0) __syncthreads();
        gl_lds16(Ag, &As[t * 8]);
        gl_lds16(Ag + 32 * 1024, &As[2048 + t * 8]);
        gl_lds16(Bg, &Bs[t * 8]);
        gl_lds16(Bg + 32 * 1024, &Bs[2048 + t * 8]);
        Ag += 64; Bg += 64;
        __syncthreads();
#pragma unroll
        for (int s = 0; s < 2; s++) {
            const int rc = (((s * 4 + q4) ^ (ln & 7)) << 3);
            short8 af[2], bfr[2];
#pragma unroll
            for (int i = 0; i < 2; i++)
                af[i] = *(const short8*)&As[(wm + i * 16 + ln) * 64 + rc];
#pragma unroll
            for (int j = 0; j < 2; j++)
                bfr[j] = *(const short8*)&Bs[(wn + j * 16 + ln) * 64 + rc];
#pragma unroll
            for (int i = 0; i < 2; i++)
#pragma unroll
                for (int j = 0; j < 2; j++)
                    acc[i][j] = __builtin_amdgcn_mfma_f32_16x16x32_bf16(af[i], bfr[j], acc[i][j], 0, 0, 0);
        }
    }
#pragma unroll
    for (int i = 0; i < 2; i++)
#pragma unroll
        for (int j = 0; j < 2; j++)
#pragma unroll
            for (int r = 0; r < 4; r++) {
                int m = m0 + wm + i * 16 + q4 * 4 + r;
                int n = n0 + wn + j * 16 + ln;
                out[(size_t)m * 1024 + n] = acc[i][j][r];
            }
}

// ---------------------------------------------------------------------------
// Workspace layout (ws >= 256 MB per fill evidence; 40 MB used, no aliasing):
//   xb    @  0 MB   4 MB  bf16 x [2048][1024]
//   Wb    @  4 MB   6 MB  bf16 Wq|Wk|Wv rows [3072][1024]
//   Wob   @ 10 MB   2 MB  bf16 Wo [1024][1024]
//   qkb   @ 12 MB   8 MB  bf16 [2048][2048] = q|k row-major (elu'd)
//   kT_b  @ 20 MB   4 MB  bf16 [16][64][2048] k^T (elu'd)
//   vT_b  @ 24 MB   4 MB  bf16 [16][64][2048] v^T
//   S_ws  @ 28 MB   4 MB  fp32 S^T per (h,c)
//   ksum  @ 32 MB 256 KB
//   attnb @ 33 MB   4 MB  bf16 [2048][1024]
// ---------------------------------------------------------------------------
extern "C" void kernel_launch(void* const* d_in, const int* in_sizes, int n_in,
                              void* d_out, int out_size, void* d_ws, size_t ws_size,
                              hipStream_t stream)
{
    const float* x  = (const float*)d_in[0];
    const float* Wq = (const float*)d_in[1];
    const float* Wk = (const float*)d_in[2];
    const float* Wv = (const float*)d_in[3];
    const float* Wo = (const float*)d_in[4];
    float* out = (float*)d_out;

    char* ws = (char*)d_ws;
    const size_t MB = 1024 * 1024;
    u16* xb    = (u16*)(ws);
    u16* Wb    = (u16*)(ws + 4 * MB);
    u16* Wob   = (u16*)(ws + 10 * MB);
    u16* qkb   = (u16*)(ws + 12 * MB);
    u16* kT_b  = (u16*)(ws + 20 * MB);
    u16* vT_b  = (u16*)(ws + 24 * MB);
    float* S_ws    = (float*)(ws + 28 * MB);
    float* ksum_ws = (float*)(ws + 32 * MB);
    u16* attnb = (u16*)(ws + 33 * MB);

    convert_all<<<2048, 256, 0, stream>>>(x, Wq, Wk, Wv, Wo, xb, Wb, Wob);
    qkv_gemm64<<<dim3(24, 32), 256, 0, stream>>>(xb, Wb, qkb, kT_b, vT_b);
    chunk_stats2<<<dim3(NCHUNK, NH), 256, 0, stream>>>(kT_b, vT_b, S_ws, ksum_ws);
    attn_out2<<<dim3(NCHUNK, NH), 256, 0, stream>>>(qkb, vT_b, S_ws, ksum_ws, attnb);
    out_gemm64<<<dim3(16, 32), 256, 0, stream>>>(attnb, Wob, out);
}